// Round 1
// baseline (91.990 us; speedup 1.0000x reference)
//
#include <hip/hip_runtime.h>

// Problem constants (fixed by setup_inputs)
constexpr int B       = 2;
constexpr int N       = 32768;
constexpr int D       = 3;
constexpr int M_FULL  = 8192;
constexpr int SUBDIV  = 8;
constexpr int M_SUB   = M_FULL / SUBDIV;   // 1024
constexpr int ROW     = M_SUB + 8;          // pad so d-rows start 8 banks apart
constexpr int BLOCK   = 256;
constexpr int BLOCKS_PER_BATCH = (N * D) / BLOCK;  // 384

__global__ __launch_bounds__(BLOCK) void deformer_kernel(
    const float* __restrict__ x,
    const float* __restrict__ dverts,
    const float* __restrict__ mverts,
    float* __restrict__ out)
{
    // [d][m] layout, row stride 1032 floats: rows start at banks {0,8,16} ->
    // the wave's three d-groups hit disjoint banks; within a group all lanes
    // read the same address (broadcast). Conflict-free ds_read_b128.
    __shared__ __align__(16) float s_dv[D * ROW];
    __shared__ __align__(16) float s_mv[D * ROW];

    const int tid = threadIdx.x;
    const int b   = blockIdx.x / BLOCKS_PER_BATCH;

    // Stage the ::8 subsample of this batch's verts into LDS.
    for (int s = tid; s < D * M_SUB; s += BLOCK) {
        const int m = s / 3;
        const int d = s - 3 * m;
        const int g = (b * M_FULL + m * SUBDIV) * D + d;
        s_dv[d * ROW + m] = dverts[g];
        s_mv[d * ROW + m] = mverts[g];
    }
    __syncthreads();

    const int o  = blockIdx.x * BLOCK + tid;   // flat (b,n,d) index == x/out index
    const float xv = x[o];
    const int d  = o % 3;

    const float* pd = s_dv + d * ROW;
    const float* pm = s_mv + d * ROW;

    // exp(-4*t) = exp2(C*t), C = -4*log2(e)
    const float C = -5.770780163555852f;

    float num0 = 0.f, num1 = 0.f, den0 = 0.f, den1 = 0.f;
    #pragma unroll 4
    for (int m = 0; m < M_SUB; m += 4) {
        const float4 dv4 = *reinterpret_cast<const float4*>(pd + m);
        const float4 mv4 = *reinterpret_cast<const float4*>(pm + m);
        const float e0 = __builtin_amdgcn_exp2f(C * fabsf(xv - dv4.x));
        const float e1 = __builtin_amdgcn_exp2f(C * fabsf(xv - dv4.y));
        const float e2 = __builtin_amdgcn_exp2f(C * fabsf(xv - dv4.z));
        const float e3 = __builtin_amdgcn_exp2f(C * fabsf(xv - dv4.w));
        num0 = fmaf(mv4.x, e0, num0);
        num1 = fmaf(mv4.y, e1, num1);
        num0 = fmaf(mv4.z, e2, num0);
        num1 = fmaf(mv4.w, e3, num1);
        den0 += e0 + e2;
        den1 += e1 + e3;
    }
    out[o] = (num0 + num1) / (den0 + den1);
}

extern "C" void kernel_launch(void* const* d_in, const int* in_sizes, int n_in,
                              void* d_out, int out_size, void* d_ws, size_t ws_size,
                              hipStream_t stream) {
    const float* x  = (const float*)d_in[0];
    const float* dv = (const float*)d_in[1];
    const float* mv = (const float*)d_in[2];
    // d_in[3] (deformation_parameters) unused by the reference math.
    float* out = (float*)d_out;

    const int grid = B * BLOCKS_PER_BATCH;  // 768
    deformer_kernel<<<grid, BLOCK, 0, stream>>>(x, dv, mv, out);
}